// Round 7
// baseline (87.560 us; speedup 1.0000x reference)
//
#include <hip/hip_runtime.h>
#include <math.h>

#define RESG 128
#define CHG 28
#define NT 767
#define NLBKT 48   // length buckets (n_proc >> 4)

template <int PAT>
static __device__ __forceinline__ float swz(float x) {
    return __int_as_float(__builtin_amdgcn_ds_swizzle(__float_as_int(x), PAT));
}

// ---------- prep: sort rays by live-length, DESCENDING ----------
__global__ __launch_bounds__(1024) void prep_sort(
    const float* __restrict__ rays_d, const float* __restrict__ rays_o,
    int* __restrict__ perm, int B)
{
    __shared__ int cnt[64];
    __shared__ int off[64];
    __shared__ unsigned char keys[4096];
    const int tid = threadIdx.x;
    if (tid < 64) cnt[tid] = 0;
    __syncthreads();
    for (int r = tid; r < B; r += 1024) {
        const float ox = rays_o[r*3+0], oy = rays_o[r*3+1], oz = rays_o[r*3+2];
        const float dx = rays_d[r*3+0], dy = rays_d[r*3+1], dz = rays_d[r*3+2];
        float txp = (1.0f - ox)/dx, txn = (-1.0f - ox)/dx;
        float typ = (1.0f - oy)/dy, tyn = (-1.0f - oy)/dy;
        float tzp = (1.0f - oz)/dz, tzn = (-1.0f - oz)/dz;
        const float start = fmaxf(fmaxf(fminf(txp,txn), fminf(typ,tyn)), fminf(tzp,tzn));
        const float stop  = fminf(fminf(fmaxf(txp,txn), fmaxf(typ,tyn)), fmaxf(tzp,tzn));
        int n_proc = (int)((stop - start) * 127.0f) + 2;
        n_proc = n_proc < 0 ? 0 : (n_proc > NT ? NT : n_proc);
        int lvl = n_proc >> 4; if (lvl > NLBKT-1) lvl = NLBKT-1;
        const int k = (NLBKT-1) - lvl;            // descending length
        keys[r] = (unsigned char)k;
        atomicAdd(&cnt[k], 1);
    }
    __syncthreads();
    if (tid < 64) {
        int v = cnt[tid];
        int incl = v;
        #pragma unroll
        for (int o2 = 1; o2 < 64; o2 <<= 1) {
            const int n = __shfl_up(incl, o2, 64);
            if ((tid & 63) >= o2) incl += n;
        }
        off[tid] = incl - v;
    }
    __syncthreads();
    for (int r = tid; r < B; r += 1024) {
        const int slot = atomicAdd(&off[keys[r]], 1);
        perm[slot] = r;
    }
}

// ---------- main ----------
__global__ __launch_bounds__(256) void nerf_grid_kernel(
    const float* __restrict__ rays_d,
    const float* __restrict__ rays_o,
    const float* __restrict__ grid,     // [128^3][28] f32, 112B rows
    const int*   __restrict__ perm,
    float* __restrict__ out_rgb,
    float* __restrict__ out_alpha,
    float* __restrict__ out_depth)
{
    const int ray  = perm[blockIdx.x];
    const int tid  = threadIdx.x;
    const int lane = tid & 63;
    const int wave = tid >> 6;

    const float EPSC   = 1e-10f;
    const float INV127 = 1.0f / 127.0f;

    __shared__ float a_lds[NT + 1];
    __shared__ float r_lds[NT + 1];
    __shared__ float g_lds[NT + 1];
    __shared__ float b_lds[NT + 1];
    __shared__ float sh_lds[12];
    __shared__ float wprod[4];
    __shared__ float red[4][5];

    // ---- per-ray setup ----
    const float ox = rays_o[ray*3+0], oy = rays_o[ray*3+1], oz = rays_o[ray*3+2];
    const float dx = rays_d[ray*3+0], dy = rays_d[ray*3+1], dz = rays_d[ray*3+2];
    const float dnorm = sqrtf(dx*dx + dy*dy + dz*dz);

    float txp = (1.0f - ox)/dx, txn = (-1.0f - ox)/dx;
    float typ = (1.0f - oy)/dy, tyn = (-1.0f - oy)/dy;
    float tzp = (1.0f - oz)/dz, tzn = (-1.0f - oz)/dz;
    const float start = fmaxf(fmaxf(fminf(txp,txn), fminf(typ,tyn)), fminf(tzp,tzn));
    const float stop  = fminf(fminf(fmaxf(txp,txn), fmaxf(typ,tyn)), fmaxf(tzp,tzn));

    int n_proc = (int)((stop - start) * 127.0f) + 2;
    n_proc = n_proc < 0 ? 0 : (n_proc > NT ? NT : n_proc);

    // SH deg-2 basis
    const float inv = 1.0f/dnorm;
    const float nx = dx*inv, ny = dy*inv, nz = dz*inv;
    {
        const float C0 = 0.28209479177387814f;
        const float C1 = 0.4886025119029199f;
        const float C20 = 1.0925484305920792f, C21 = -1.0925484305920792f;
        const float C22 = 0.31539156525252005f;
        const float C23 = -1.0925484305920792f, C24 = 0.5462742152960396f;
        if (tid == 0) {
            sh_lds[0] = C0;
            sh_lds[1] = -C1*ny;
            sh_lds[2] =  C1*nz;
            sh_lds[3] = -C1*nx;
            sh_lds[4] = C20*nx*ny;
            sh_lds[5] = C21*ny*nz;
            sh_lds[6] = C22*(2.0f*nz*nz - nx*nx - ny*ny);
            sh_lds[7] = C23*nx*nz;
            sh_lds[8] = C24*(nx*nx - ny*ny);
            sh_lds[9] = 0.0f; sh_lds[10] = 0.0f; sh_lds[11] = 0.0f;
        }
    }
    __syncthreads();

    // ---- per-lane channel-slice coefficients (once per ray) ----
    const int samp = lane >> 3;
    const int j    = lane & 7;
    float cR[4], cG[4], cB[4];
    #pragma unroll
    for (int m = 0; m < 4; ++m) {
        const int ch = 4*j + m;
        const int iR = ch      > 11 ? 11 : ch;
        const int iG = (ch-9)  < 0 ? 0 : ((ch-9)  > 11 ? 11 : (ch-9));
        const int iB = (ch-18) < 0 ? 0 : ((ch-18) > 11 ? 11 : (ch-18));
        cR[m] = (ch < 9)               ? sh_lds[iR] : 0.0f;
        cG[m] = (ch >= 9 && ch < 18)   ? sh_lds[iG] : 0.0f;
        cB[m] = (ch >= 18 && ch < 27)  ? sh_lds[iB] : 0.0f;
    }
    const float cS3 = (j == 6) ? 1.0f : 0.0f;   // sigma = channel 27
    const int chunk_off = (j < 7 ? j : 6) << 4; // bytes
    const char* gridc = (const char*)grid;

    // ---- phase 1: lane=chunk, instruction=corner; wave handles 8 samples/iter ----
    for (int base = wave*8; base < n_proc; base += 32) {
        const int s = base + samp;
        const float t0 = fminf(start + (float)(s+1)*INV127, stop);
        const float t1 = fminf(start + (float)(s+2)*INV127, stop);
        const float dist = (t1 - t0) * dnorm;
        const bool live = (s < n_proc) && (dist > 0.0f);

        // clamp to [0,127]: guarantees base cell in-bounds (fp slop at faces)
        const float gx = fminf(fmaxf((ox + t0*dx + 1.0f)*63.5f, 0.0f), 127.0f);
        const float gy = fminf(fmaxf((oy + t0*dy + 1.0f)*63.5f, 0.0f), 127.0f);
        const float gz = fminf(fmaxf((oz + t0*dz + 1.0f)*63.5f, 0.0f), 127.0f);
        const float fx0 = floorf(gx), fy0 = floorf(gy), fz0 = floorf(gz);
        const float fx = gx - fx0, fy = gy - fy0, fz = gz - fz0;
        const int ix = (int)fx0, iy = (int)fy0, iz = (int)fz0;

        // base row byte address (+ this lane's chunk offset)
        const int Bv = ((iz*RESG + iy)*RESG + ix)*112 + chunk_off;
        const int offx = (ix < RESG-1) ? 112 : 0;            // clamp == zero offset (weight=0 there)
        const int offy = (iy < RESG-1) ? 112*RESG : 0;
        const int offz = (iz < RESG-1) ? 112*RESG*RESG : 0;
        int offs[8];
        offs[0] = 0;           offs[1] = offx;
        offs[2] = offy;        offs[3] = offx + offy;
        offs[4] = offz;        offs[5] = offz + offx;
        offs[6] = offz + offy; offs[7] = offz + offx + offy;

        // corner weights (live folded in)
        const float liveF = live ? 1.0f : 0.0f;
        const float wx1 = fx, wx0 = 1.0f - fx;
        const float wy1 = fy, wy0 = 1.0f - fy;
        const float wz1 = fz*liveF, wz0 = (1.0f - fz)*liveF;
        const float w00 = wx0*wy0, w10 = wx1*wy0, w01 = wx0*wy1, w11 = wx1*wy1;
        float wc[8];
        wc[0] = w00*wz0; wc[1] = w10*wz0; wc[2] = w01*wz0; wc[3] = w11*wz0;
        wc[4] = w00*wz1; wc[5] = w10*wz1; wc[6] = w01*wz1; wc[7] = w11*wz1;

        // 8 corner loads: lanes j=0..6 cover the full 112B row contiguously
        float av0 = 0.0f, av1 = 0.0f, av2 = 0.0f, av3 = 0.0f;
        #pragma unroll
        for (int i = 0; i < 8; ++i) {
            const float4 v = *(const float4*)(gridc + (size_t)(unsigned)(Bv + offs[i]));
            av0 = fmaf(wc[i], v.x, av0);
            av1 = fmaf(wc[i], v.y, av1);
            av2 = fmaf(wc[i], v.z, av2);
            av3 = fmaf(wc[i], v.w, av3);
        }

        // per-lane channel-slice dots
        float rr = av0*cR[0] + av1*cR[1] + av2*cR[2] + av3*cR[3];
        float gg = av0*cG[0] + av1*cG[1] + av2*cG[2] + av3*cG[3];
        float bb = av0*cB[0] + av1*cB[1] + av2*cB[2] + av3*cB[3];
        float sg = av3*cS3;

        // reduce over the 8 chunk lanes (xor 1,2,4)
        rr += swz<0x041F>(rr); gg += swz<0x041F>(gg); bb += swz<0x041F>(bb); sg += swz<0x041F>(sg);
        rr += swz<0x081F>(rr); gg += swz<0x081F>(gg); bb += swz<0x081F>(bb); sg += swz<0x081F>(sg);
        rr += swz<0x101F>(rr); gg += swz<0x101F>(gg); bb += swz<0x101F>(bb); sg += swz<0x101F>(sg);

        if (j == 0 && s < n_proc) {
            a_lds[s] = 1.0f - expf(-fmaxf(sg, 0.0f)*dist);   // dist==0 -> exactly 0
            r_lds[s] = 1.0f/(1.0f + expf(-rr));
            g_lds[s] = 1.0f/(1.0f + expf(-gg));
            b_lds[s] = 1.0f/(1.0f + expf(-bb));
        }
    }
    __syncthreads();

    // coalesced alpha output (zeros for dead range)
    for (int s = tid; s < NT; s += 256)
        out_alpha[(size_t)ray*NT + s] = (s < n_proc) ? a_lds[s] : 0.0f;

    // ---- phase 2: per-thread 3 consecutive samples ----
    float a_r[3], q_r[3], t_r[3], rr_r[3], gg_r[3], bb_r[3];
    #pragma unroll
    for (int k = 0; k < 3; ++k) {
        const int s = tid*3 + k;
        float a = 0.0f, rr = 0.0f, gg = 0.0f, bb = 0.0f, tt = 0.0f;
        if (s < NT) {
            tt = fminf(start + (float)(s+1)*INV127, stop);
            if (s < n_proc) {
                a = a_lds[s];
                rr = r_lds[s]; gg = g_lds[s]; bb = b_lds[s];
            }
        }
        a_r[k] = a; q_r[k] = (s < NT) ? (1.0f - a + EPSC) : 1.0f;
        t_r[k] = tt; rr_r[k] = rr; gg_r[k] = gg; bb_r[k] = bb;
    }

    // ---- block-wide exclusive product scan ----
    const float P = q_r[0]*q_r[1]*q_r[2];
    float incl = P;
    #pragma unroll
    for (int off2 = 1; off2 < 64; off2 <<= 1) {
        const float n = __shfl_up(incl, off2, 64);
        if (lane >= off2) incl *= n;
    }
    float excl = __shfl_up(incl, 1, 64);
    if (lane == 0) excl = 1.0f;

    if (lane == 63) wprod[wave] = incl;
    __syncthreads();
    float wpre = 1.0f;
    for (int w2 = 0; w2 < 4; ++w2) if (w2 < wave) wpre *= wprod[w2];

    // ---- phase 3: weighted accumulation ----
    float cum = wpre * excl;
    float accA = 0.0f, accR = 0.0f, accG = 0.0f, accB = 0.0f, accD = 0.0f;
    #pragma unroll
    for (int k = 0; k < 3; ++k) {
        const float abs_l = a_r[k] * cum;
        accA += abs_l;
        accR += abs_l * rr_r[k];
        accG += abs_l * gg_r[k];
        accB += abs_l * bb_r[k];
        accD += abs_l * t_r[k];
        cum *= q_r[k];
    }

    #pragma unroll
    for (int off2 = 32; off2 > 0; off2 >>= 1) {
        accA += __shfl_down(accA, off2, 64);
        accR += __shfl_down(accR, off2, 64);
        accG += __shfl_down(accG, off2, 64);
        accB += __shfl_down(accB, off2, 64);
        accD += __shfl_down(accD, off2, 64);
    }
    if (lane == 0) {
        red[wave][0] = accA; red[wave][1] = accR; red[wave][2] = accG;
        red[wave][3] = accB; red[wave][4] = accD;
    }
    __syncthreads();
    if (tid == 0) {
        float A = 0.0f, R = 0.0f, G = 0.0f, Bv2 = 0.0f, D = 0.0f;
        #pragma unroll
        for (int w2 = 0; w2 < 4; ++w2) {
            A += red[w2][0]; R += red[w2][1]; G += red[w2][2];
            Bv2 += red[w2][3]; D += red[w2][4];
        }
        const float bg = 1.0f - A;
        out_rgb[ray*3+0] = R   + bg;
        out_rgb[ray*3+1] = G   + bg;
        out_rgb[ray*3+2] = Bv2 + bg;
        out_depth[ray] = D;
    }
}

extern "C" void kernel_launch(void* const* d_in, const int* in_sizes, int n_in,
                              void* d_out, int out_size, void* d_ws, size_t ws_size,
                              hipStream_t stream) {
    const float* rays_d = (const float*)d_in[0];
    const float* rays_o = (const float*)d_in[1];
    const float* grid   = (const float*)d_in[2];
    const int B = in_sizes[0] / 3;   // 4096

    float* out       = (float*)d_out;
    float* out_rgb   = out;
    float* out_alpha = out + (size_t)B*3;
    float* out_depth = out + (size_t)B*3 + (size_t)B*NT;

    int* perm = (int*)d_ws;

    prep_sort<<<1, 1024, 0, stream>>>(rays_d, rays_o, perm, B);
    nerf_grid_kernel<<<B, 256, 0, stream>>>(rays_d, rays_o, grid, perm,
                                            out_rgb, out_alpha, out_depth);
}